// Round 17
// baseline (628.637 us; speedup 1.0000x reference)
//
#include <hip/hip_runtime.h>

#define V_N 100000
#define J_N 24
#define NB_N 10
#define NP_N 207
#define FLAT_P 621
#define FACE_I 600000
#define CHUNKS 50
#define CHUNK_V 2000
#define K1_BLK 1172       // ceil(300000/256)
#define F_BLK  587        // ceil(150000/256)
#define NS4 (V_N * FLAT_P / 4)   // 15,525,000 float4 slots of posedirs

__device__ __constant__ int PARENT_D[24] = {
    -1, 0, 0, 0, 1, 2, 3, 4, 5, 6, 7, 8, 9, 9, 9, 12, 13, 14, 16, 17, 18, 19, 20, 21
};

typedef __attribute__((address_space(3))) void lds_void;
typedef __attribute__((address_space(1))) void glb_void;

__device__ __forceinline__ float wave_sum64(float x) {
    float t;
    t = __int_as_float(__builtin_amdgcn_update_dpp(0, __float_as_int(x), 0x111, 0xf, 0xf, true)); x += t;
    t = __int_as_float(__builtin_amdgcn_update_dpp(0, __float_as_int(x), 0x112, 0xf, 0xf, true)); x += t;
    t = __int_as_float(__builtin_amdgcn_update_dpp(0, __float_as_int(x), 0x114, 0xf, 0xf, true)); x += t;
    t = __int_as_float(__builtin_amdgcn_update_dpp(0, __float_as_int(x), 0x118, 0xf, 0xf, true)); x += t;
    t = __int_as_float(__builtin_amdgcn_update_dpp(0, __float_as_int(x), 0x142, 0xa, 0xf, true)); x += t;
    t = __int_as_float(__builtin_amdgcn_update_dpp(0, __float_as_int(x), 0x143, 0xc, 0xf, true)); x += t;
    return __int_as_float(__builtin_amdgcn_readlane(__float_as_int(x), 63));
}

// ---------------- kA: shape blend + faces copy (R12-proven, unchanged) ----------------
__global__ __launch_bounds__(256) void kA_shape_faces(const float* __restrict__ shapedirs,
                                                      const float* __restrict__ vtemp,
                                                      const float* __restrict__ beta,
                                                      float* __restrict__ vshaped,
                                                      const int4* __restrict__ faces4,
                                                      float* __restrict__ out) {
    int b = blockIdx.x;
    if (b < K1_BLK) {
        int i = b * 256 + threadIdx.x;
        if (i >= V_N * 3) return;
        const float2* sd2 = reinterpret_cast<const float2*>(shapedirs + (size_t)i * NB_N);
        float2 p0 = sd2[0], p1 = sd2[1], p2 = sd2[2], p3 = sd2[3], p4 = sd2[4];
        float acc = vtemp[i];
        acc += p0.x * beta[0] + p0.y * beta[1];
        acc += p1.x * beta[2] + p1.y * beta[3];
        acc += p2.x * beta[4] + p2.y * beta[5];
        acc += p3.x * beta[6] + p3.y * beta[7];
        acc += p4.x * beta[8] + p4.y * beta[9];
        vshaped[i] = acc;
    } else {
        int i = (b - K1_BLK) * 256 + threadIdx.x;
        if (i < FACE_I / 4) {
            int4 f = faces4[i];
            float4* fdst = reinterpret_cast<float4*>(out + 300000);
            fdst[i] = make_float4((float)f.x, (float)f.y, (float)f.z, (float)f.w);
        }
    }
}

// ---------------- kB: partial GEMV — transposed partials [c][72] (R14-proven) ----------------
__global__ __launch_bounds__(256) void kB_partial(const float* __restrict__ Jreg,
                                                  const float* __restrict__ vshaped,
                                                  float* __restrict__ partials) {
    int c = blockIdx.x, j = blockIdx.y;
    int t = threadIdx.x;
    const float* row = Jreg + (size_t)j * V_N + (size_t)c * CHUNK_V;
    const float* vs  = vshaped + (size_t)c * CHUNK_V * 3;
    float s0 = 0.f, s1 = 0.f, s2 = 0.f;
    for (int i = t; i < CHUNK_V; i += 256) {
        float w = row[i];
        s0 += w * vs[i * 3 + 0];
        s1 += w * vs[i * 3 + 1];
        s2 += w * vs[i * 3 + 2];
    }
    for (int off = 32; off > 0; off >>= 1) {
        s0 += __shfl_xor(s0, off, 64);
        s1 += __shfl_xor(s1, off, 64);
        s2 += __shfl_xor(s2, off, 64);
    }
    __shared__ float ls[3][4];
    int wv = t >> 6;
    if ((t & 63) == 0) { ls[0][wv] = s0; ls[1][wv] = s1; ls[2][wv] = s2; }
    __syncthreads();
    if (t == 0) {
        float* p = partials + (size_t)c * 72 + j * 3;
        p[0] = ls[0][0] + ls[0][1] + ls[0][2] + ls[0][3];
        p[1] = ls[1][0] + ls[1][1] + ls[1][2] + ls[1][3];
        p[2] = ls[2][0] + ls[2][1] + ls[2][2] + ls[2][3];
    }
}

// ---------------- kC: parallel Jts reduce + Rodrigues + 640-lrot + FK + A (R15-proven) ----------------
__global__ __launch_bounds__(128) void kC_fk(const float* __restrict__ pose,
                                             const float* __restrict__ partials,
                                             float* __restrict__ ws_lrot,
                                             float* __restrict__ ws_A) {
    __shared__ float R[24][9];
    __shared__ float G[24][12];
    __shared__ float Jts[24][3];
    int t = threadIdx.x;
    if (t < 72) {
        float s = 0.f;
        #pragma unroll
        for (int c = 0; c < CHUNKS; ++c) s += partials[c * 72 + t];
        (&Jts[0][0])[t] = s;
    }
    if (t < 24) {
        float x = pose[t * 3 + 0], y = pose[t * 3 + 1], z = pose[t * 3 + 2];
        float th = sqrtf(x * x + y * y + z * z) + 1e-8f;
        float inv = 1.0f / th;
        float rx = x * inv, ry = y * inv, rz = z * inv;
        float c = cosf(th), s = sinf(th), ic = 1.0f - c;
        R[t][0] = c + ic * rx * rx;      R[t][1] = ic * rx * ry - s * rz;  R[t][2] = ic * rx * rz + s * ry;
        R[t][3] = ic * ry * rx + s * rz; R[t][4] = c + ic * ry * ry;       R[t][5] = ic * ry * rz - s * rx;
        R[t][6] = ic * rz * rx - s * ry; R[t][7] = ic * rz * ry + s * rx;  R[t][8] = c + ic * rz * rz;
    }
    __syncthreads();
    for (int f = t; f < 640; f += 128) {
        float val = 0.0f;
        if (f < FLAT_P) {
            int p = f % NP_N;
            int j = 1 + p / 9;
            int e = p % 9;
            val = R[j][e] - ((e == 0 || e == 4 || e == 8) ? 1.0f : 0.0f);
        }
        ws_lrot[f] = val;
    }
    if (t < 12) {
        int r = t >> 2, c = t & 3;
        G[0][t] = (c < 3) ? R[0][r * 3 + c] : Jts[0][r];
    }
    __syncthreads();
    for (int i = 1; i < J_N; ++i) {
        int p = PARENT_D[i];
        if (t < 12) {
            int r = t >> 2, c = t & 3;
            float sum = (c == 3) ? G[p][r * 4 + 3] : 0.0f;
            #pragma unroll
            for (int k = 0; k < 3; ++k) {
                float loc = (c < 3) ? R[i][k * 3 + c] : (Jts[i][k] - Jts[p][k]);
                sum += G[p][r * 4 + k] * loc;
            }
            G[i][t] = sum;
        }
        __syncthreads();
    }
    if (t < 72) {
        int j = t / 3, r = t % 3;
        float g0 = G[j][r * 4 + 0], g1 = G[j][r * 4 + 1], g2 = G[j][r * 4 + 2], g3 = G[j][r * 4 + 3];
        float corr = g0 * Jts[j][0] + g1 * Jts[j][1] + g2 * Jts[j][2];
        ws_A[j * 12 + r * 4 + 0] = g0;
        ws_A[j * 12 + r * 4 + 1] = g1;
        ws_A[j * 12 + r * 4 + 2] = g2;
        ws_A[j * 12 + r * 4 + 3] = g3 - corr;
    }
}

// ---------------- kD: pose blend + skinning — DMA staging (R16-proven, unchanged) ----------------
__global__ __launch_bounds__(256) void kD_main(const float* __restrict__ posedirs,
                                               const float* __restrict__ weights,
                                               const float* __restrict__ vshaped,
                                               const float* __restrict__ ws_lrot,
                                               const float* __restrict__ ws_A,
                                               const float* __restrict__ trans,
                                               float* __restrict__ out) {
    __shared__ __align__(16) float sP[4 * FLAT_P];
    __shared__ float sL[640];
    __shared__ float sA[288];
    int tid = threadIdx.x;
    int lane = tid & 63;
    int w = tid >> 6;

    const char* gbase = reinterpret_cast<const char*>(posedirs) + (size_t)blockIdx.x * 9936;
    char* lbase = reinterpret_cast<char*>(sP);
    #pragma unroll
    for (int k = 0; k < 3; ++k) {
        int chunk = w + k * 4;
        if (chunk < 10) {
            int nlanes = (chunk == 9) ? 45 : 64;
            if (lane < nlanes) {
                const void* g = gbase + chunk * 1024 + lane * 16;
                __builtin_amdgcn_global_load_lds((const glb_void*)g,
                                                 (lds_void*)(lbase + chunk * 1024),
                                                 16, 0, 0);
            }
        }
    }
    for (int i = tid; i < 640; i += 256) sL[i] = ws_lrot[i];
    for (int i = tid; i < 288; i += 256) sA[i] = ws_A[i];
    __syncthreads();

    int v = blockIdx.x * 4 + w;

    const float* pd = sP + w * FLAT_P;
    float a0 = 0.f, a1 = 0.f, a2 = 0.f;
    #pragma unroll
    for (int k = 0; k < 10; ++k) {
        int f = lane + k * 64;
        if (f < FLAT_P) {
            float val = pd[f] * sL[f];
            if (f < 207)      a0 += val;
            else if (f < 414) a1 += val;
            else              a2 += val;
        }
    }
    float vp0 = wave_sum64(a0) + vshaped[v * 3 + 0];
    float vp1 = wave_sum64(a1) + vshaped[v * 3 + 1];
    float vp2 = wave_sum64(a2) + vshaped[v * 3 + 2];

    float r0 = 0.f, r1 = 0.f, r2 = 0.f;
    if (lane < J_N) {
        float wgt = weights[(size_t)v * J_N + lane];
        const float* A = &sA[lane * 12];
        r0 = wgt * (A[0] * vp0 + A[1] * vp1 + A[2]  * vp2 + A[3]);
        r1 = wgt * (A[4] * vp0 + A[5] * vp1 + A[6]  * vp2 + A[7]);
        r2 = wgt * (A[8] * vp0 + A[9] * vp1 + A[10] * vp2 + A[11]);
    }
    float s0 = wave_sum64(r0);
    float s1 = wave_sum64(r1);
    float s2 = wave_sum64(r2);

    if (lane < 3) {
        float res = (lane == 0) ? s0 : (lane == 1) ? s1 : s2;
        out[v * 3 + lane] = res + trans[lane];
    }
}

// ================= PROBE pR: ideal float4 grid-stride read of posedirs, 6 reps =================
// Launched twice: #1's first rep = cold pass; #2 = all-L3-warm. cold = pR1 - (5/6)*pR2.
__global__ __launch_bounds__(256) void pR(const float4* __restrict__ p4, float* __restrict__ scr) {
    int gtid = blockIdx.x * 256 + threadIdx.x;
    int stride = gridDim.x * 256;
    float s = 0.f;
    #pragma unroll 1
    for (int rep = 0; rep < 6; ++rep) {
        float a0 = 0.f, a1 = 0.f, a2 = 0.f, a3 = 0.f;
        int i = gtid;
        for (; i + 3 * stride < NS4; i += 4 * stride) {
            float4 a = p4[i], b = p4[i + stride], c = p4[i + 2 * stride], d = p4[i + 3 * stride];
            a0 += a.x + a.y + a.z + a.w;
            a1 += b.x + b.y + b.z + b.w;
            a2 += c.x + c.y + c.z + c.w;
            a3 += d.x + d.y + d.z + d.w;
        }
        for (; i < NS4; i += stride) { float4 a = p4[i]; a0 += a.x + a.y + a.z + a.w; }
        s += a0 + a1 + a2 + a3;
        asm volatile("" ::: "memory");
    }
    float t = wave_sum64(s);
    if ((threadIdx.x & 63) == 0) scr[blockIdx.x * 4 + (threadIdx.x >> 6)] = t;
}

// ================= PROBE pS: kD's DMA+dot structure only (warm), 6 reps =================
__global__ __launch_bounds__(256) void pS(const float* __restrict__ posedirs,
                                          const float* __restrict__ ws_lrot,
                                          float* __restrict__ scr) {
    __shared__ __align__(16) float sP[4 * FLAT_P];
    __shared__ float sL[640];
    int tid = threadIdx.x;
    int lane = tid & 63;
    int w = tid >> 6;
    #pragma unroll 1
    for (int rep = 0; rep < 6; ++rep) {
        const char* gbase = reinterpret_cast<const char*>(posedirs) + (size_t)blockIdx.x * 9936;
        char* lbase = reinterpret_cast<char*>(sP);
        #pragma unroll
        for (int k = 0; k < 3; ++k) {
            int chunk = w + k * 4;
            if (chunk < 10) {
                int nlanes = (chunk == 9) ? 45 : 64;
                if (lane < nlanes) {
                    const void* g = gbase + chunk * 1024 + lane * 16;
                    __builtin_amdgcn_global_load_lds((const glb_void*)g,
                                                     (lds_void*)(lbase + chunk * 1024),
                                                     16, 0, 0);
                }
            }
        }
        for (int i = tid; i < 640; i += 256) sL[i] = ws_lrot[i];
        __syncthreads();
        const float* pd = sP + w * FLAT_P;
        float a0 = 0.f, a1 = 0.f, a2 = 0.f;
        #pragma unroll
        for (int k = 0; k < 10; ++k) {
            int f = lane + k * 64;
            if (f < FLAT_P) {
                float val = pd[f] * sL[f];
                if (f < 207)      a0 += val;
                else if (f < 414) a1 += val;
                else              a2 += val;
            }
        }
        asm volatile("" :: "v"(a0), "v"(a1), "v"(a2));   // keep live, no DCE
        __syncthreads();                                 // sP reuse across reps
    }
}

extern "C" void kernel_launch(void* const* d_in, const int* in_sizes, int n_in,
                              void* d_out, int out_size, void* d_ws, size_t ws_size,
                              hipStream_t stream) {
    const float* beta      = (const float*)d_in[0];
    const float* pose      = (const float*)d_in[1];
    const float* trans     = (const float*)d_in[2];
    const float* shapedirs = (const float*)d_in[3];
    const float* v_template= (const float*)d_in[4];
    const float* J_reg     = (const float*)d_in[5];
    const float* posedirs  = (const float*)d_in[6];
    const float* weights   = (const float*)d_in[7];
    const int*   faces     = (const int*)d_in[8];

    float* out = (float*)d_out;

    // ws layout (floats)
    float* ws       = (float*)d_ws;
    float* vshaped  = ws;                 // 300000
    float* ws_lrot  = ws + 300080;        // 640
    float* ws_A     = ws + 300720;        // 288
    float* partials = ws + 301008;        // [c][72] = 3600
    float* scr      = ws + 400000;        // probe scratch

    // ---- probes first: pR#1 takes the replay's cold pass; pR#2 all-warm; pS warm ----
    pR<<<2048, 256, 0, stream>>>((const float4*)posedirs, scr);
    pR<<<2048, 256, 0, stream>>>((const float4*)posedirs, scr + 8192);
    pS<<<V_N / 4, 256, 0, stream>>>(posedirs, ws_lrot, scr);

    // ---- real pipeline (R16 structure, byte-identical) ----
    kA_shape_faces<<<K1_BLK + F_BLK, 256, 0, stream>>>(shapedirs, v_template, beta, vshaped,
                                                       (const int4*)faces, out);
    kB_partial<<<dim3(CHUNKS, J_N), 256, 0, stream>>>(J_reg, vshaped, partials);
    kC_fk<<<1, 128, 0, stream>>>(pose, partials, ws_lrot, ws_A);
    kD_main<<<V_N / 4, 256, 0, stream>>>(posedirs, weights, vshaped, ws_lrot, ws_A, trans, out);
}

// Round 18
// 80.522 us; speedup vs baseline: 7.8070x; 7.8070x over previous
//
#include <hip/hip_runtime.h>

#define V_N 100000
#define J_N 24
#define NB_N 10
#define NP_N 207
#define FLAT_P 621
#define FACE_I 600000
#define CHUNKS 50
#define CHUNK_V 2000
#define K1_BLK 1172       // ceil(300000/256)
#define F_BLK  587        // ceil(150000/256)
#define GPB 10            // groups (4 vertices) per block in kD
#define GRP_B 9936        // bytes per group = 4*621*4

__device__ __constant__ int PARENT_D[24] = {
    -1, 0, 0, 0, 1, 2, 3, 4, 5, 6, 7, 8, 9, 9, 9, 12, 13, 14, 16, 17, 18, 19, 20, 21
};

typedef __attribute__((address_space(3))) void lds_void;
typedef __attribute__((address_space(1))) void glb_void;

__device__ __forceinline__ float wave_sum64(float x) {
    float t;
    t = __int_as_float(__builtin_amdgcn_update_dpp(0, __float_as_int(x), 0x111, 0xf, 0xf, true)); x += t;
    t = __int_as_float(__builtin_amdgcn_update_dpp(0, __float_as_int(x), 0x112, 0xf, 0xf, true)); x += t;
    t = __int_as_float(__builtin_amdgcn_update_dpp(0, __float_as_int(x), 0x114, 0xf, 0xf, true)); x += t;
    t = __int_as_float(__builtin_amdgcn_update_dpp(0, __float_as_int(x), 0x118, 0xf, 0xf, true)); x += t;
    t = __int_as_float(__builtin_amdgcn_update_dpp(0, __float_as_int(x), 0x142, 0xa, 0xf, true)); x += t;
    t = __int_as_float(__builtin_amdgcn_update_dpp(0, __float_as_int(x), 0x143, 0xc, 0xf, true)); x += t;
    return __int_as_float(__builtin_amdgcn_readlane(__float_as_int(x), 63));
}

// ---------------- kA: shape blend + faces copy (R12-proven, unchanged) ----------------
__global__ __launch_bounds__(256) void kA_shape_faces(const float* __restrict__ shapedirs,
                                                      const float* __restrict__ vtemp,
                                                      const float* __restrict__ beta,
                                                      float* __restrict__ vshaped,
                                                      const int4* __restrict__ faces4,
                                                      float* __restrict__ out) {
    int b = blockIdx.x;
    if (b < K1_BLK) {
        int i = b * 256 + threadIdx.x;
        if (i >= V_N * 3) return;
        const float2* sd2 = reinterpret_cast<const float2*>(shapedirs + (size_t)i * NB_N);
        float2 p0 = sd2[0], p1 = sd2[1], p2 = sd2[2], p3 = sd2[3], p4 = sd2[4];
        float acc = vtemp[i];
        acc += p0.x * beta[0] + p0.y * beta[1];
        acc += p1.x * beta[2] + p1.y * beta[3];
        acc += p2.x * beta[4] + p2.y * beta[5];
        acc += p3.x * beta[6] + p3.y * beta[7];
        acc += p4.x * beta[8] + p4.y * beta[9];
        vshaped[i] = acc;
    } else {
        int i = (b - K1_BLK) * 256 + threadIdx.x;
        if (i < FACE_I / 4) {
            int4 f = faces4[i];
            float4* fdst = reinterpret_cast<float4*>(out + 300000);
            fdst[i] = make_float4((float)f.x, (float)f.y, (float)f.z, (float)f.w);
        }
    }
}

// ---------------- kB: partial GEMV — transposed partials [c][72] (R14-proven) ----------------
__global__ __launch_bounds__(256) void kB_partial(const float* __restrict__ Jreg,
                                                  const float* __restrict__ vshaped,
                                                  float* __restrict__ partials) {
    int c = blockIdx.x, j = blockIdx.y;
    int t = threadIdx.x;
    const float* row = Jreg + (size_t)j * V_N + (size_t)c * CHUNK_V;
    const float* vs  = vshaped + (size_t)c * CHUNK_V * 3;
    float s0 = 0.f, s1 = 0.f, s2 = 0.f;
    for (int i = t; i < CHUNK_V; i += 256) {
        float w = row[i];
        s0 += w * vs[i * 3 + 0];
        s1 += w * vs[i * 3 + 1];
        s2 += w * vs[i * 3 + 2];
    }
    for (int off = 32; off > 0; off >>= 1) {
        s0 += __shfl_xor(s0, off, 64);
        s1 += __shfl_xor(s1, off, 64);
        s2 += __shfl_xor(s2, off, 64);
    }
    __shared__ float ls[3][4];
    int wv = t >> 6;
    if ((t & 63) == 0) { ls[0][wv] = s0; ls[1][wv] = s1; ls[2][wv] = s2; }
    __syncthreads();
    if (t == 0) {
        float* p = partials + (size_t)c * 72 + j * 3;
        p[0] = ls[0][0] + ls[0][1] + ls[0][2] + ls[0][3];
        p[1] = ls[1][0] + ls[1][1] + ls[1][2] + ls[1][3];
        p[2] = ls[2][0] + ls[2][1] + ls[2][2] + ls[2][3];
    }
}

// ---------------- kC: parallel Jts reduce + Rodrigues + 640-lrot + FK + A (R15-proven) ----------------
__global__ __launch_bounds__(128) void kC_fk(const float* __restrict__ pose,
                                             const float* __restrict__ partials,
                                             float* __restrict__ ws_lrot,
                                             float* __restrict__ ws_A) {
    __shared__ float R[24][9];
    __shared__ float G[24][12];
    __shared__ float Jts[24][3];
    int t = threadIdx.x;
    if (t < 72) {
        float s = 0.f;
        #pragma unroll
        for (int c = 0; c < CHUNKS; ++c) s += partials[c * 72 + t];
        (&Jts[0][0])[t] = s;
    }
    if (t < 24) {
        float x = pose[t * 3 + 0], y = pose[t * 3 + 1], z = pose[t * 3 + 2];
        float th = sqrtf(x * x + y * y + z * z) + 1e-8f;
        float inv = 1.0f / th;
        float rx = x * inv, ry = y * inv, rz = z * inv;
        float c = cosf(th), s = sinf(th), ic = 1.0f - c;
        R[t][0] = c + ic * rx * rx;      R[t][1] = ic * rx * ry - s * rz;  R[t][2] = ic * rx * rz + s * ry;
        R[t][3] = ic * ry * rx + s * rz; R[t][4] = c + ic * ry * ry;       R[t][5] = ic * ry * rz - s * rx;
        R[t][6] = ic * rz * rx - s * ry; R[t][7] = ic * rz * ry + s * rx;  R[t][8] = c + ic * rz * rz;
    }
    __syncthreads();
    for (int f = t; f < 640; f += 128) {
        float val = 0.0f;
        if (f < FLAT_P) {
            int p = f % NP_N;
            int j = 1 + p / 9;
            int e = p % 9;
            val = R[j][e] - ((e == 0 || e == 4 || e == 8) ? 1.0f : 0.0f);
        }
        ws_lrot[f] = val;
    }
    if (t < 12) {
        int r = t >> 2, c = t & 3;
        G[0][t] = (c < 3) ? R[0][r * 3 + c] : Jts[0][r];
    }
    __syncthreads();
    for (int i = 1; i < J_N; ++i) {
        int p = PARENT_D[i];
        if (t < 12) {
            int r = t >> 2, c = t & 3;
            float sum = (c == 3) ? G[p][r * 4 + 3] : 0.0f;
            #pragma unroll
            for (int k = 0; k < 3; ++k) {
                float loc = (c < 3) ? R[i][k * 3 + c] : (Jts[i][k] - Jts[p][k]);
                sum += G[p][r * 4 + k] * loc;
            }
            G[i][t] = sum;
        }
        __syncthreads();
    }
    if (t < 72) {
        int j = t / 3, r = t % 3;
        float g0 = G[j][r * 4 + 0], g1 = G[j][r * 4 + 1], g2 = G[j][r * 4 + 2], g3 = G[j][r * 4 + 3];
        float corr = g0 * Jts[j][0] + g1 * Jts[j][1] + g2 * Jts[j][2];
        ws_A[j * 12 + r * 4 + 0] = g0;
        ws_A[j * 12 + r * 4 + 1] = g1;
        ws_A[j * 12 + r * 4 + 2] = g2;
        ws_A[j * 12 + r * 4 + 3] = g3 - corr;
    }
}

// ---------------- kD: pose blend + skinning — DOUBLE-BUFFERED DMA pipeline ----------------
// Block processes GPB=10 groups of 4 vertices. Per iteration: issue DMA for group g+1
// into buf[1-cur] BEFORE computing buf[cur]; end-of-iteration barrier drains the DMA
// after compute -> HBM latency hides under the reduction tail. Compute body = R16.
__global__ __launch_bounds__(256) void kD_main(const float* __restrict__ posedirs,
                                               const float* __restrict__ weights,
                                               const float* __restrict__ vshaped,
                                               const float* __restrict__ ws_lrot,
                                               const float* __restrict__ ws_A,
                                               const float* __restrict__ trans,
                                               float* __restrict__ out) {
    __shared__ __align__(16) float sP[2][4 * FLAT_P];   // 2 x 9936 B
    __shared__ float sL[640];
    __shared__ float sA[288];
    int tid = threadIdx.x;
    int lane = tid & 63;
    int w = tid >> 6;

    auto do_dma = [&](int group, int buf) {
        const char* gb = reinterpret_cast<const char*>(posedirs) + (size_t)group * GRP_B;
        char* lb = reinterpret_cast<char*>(sP[buf]);
        #pragma unroll
        for (int k = 0; k < 3; ++k) {
            int chunk = w + k * 4;                 // waves 0..3 cover chunks 0..9
            if (chunk < 10) {
                int nlanes = (chunk == 9) ? 45 : 64;   // chunk 9 = 720 B
                if (lane < nlanes) {
                    __builtin_amdgcn_global_load_lds(
                        (const glb_void*)(gb + chunk * 1024 + lane * 16),
                        (lds_void*)(lb + chunk * 1024), 16, 0, 0);
                }
            }
        }
    };

    int g0 = blockIdx.x * GPB;
    do_dma(g0, 0);                                  // prologue
    for (int i = tid; i < 640; i += 256) sL[i] = ws_lrot[i];
    for (int i = tid; i < 288; i += 256) sA[i] = ws_A[i];
    __syncthreads();                                // buf0 + tables ready

    int cur = 0;
    #pragma unroll 1
    for (int g = 0; g < GPB; ++g) {
        if (g + 1 < GPB) do_dma(g0 + g + 1, cur ^ 1);   // overlaps compute below

        int v = (g0 + g) * 4 + w;
        const float* pd = sP[cur] + w * FLAT_P;
        float a0 = 0.f, a1 = 0.f, a2 = 0.f;
        #pragma unroll
        for (int k = 0; k < 10; ++k) {
            int f = lane + k * 64;
            if (f < FLAT_P) {
                float val = pd[f] * sL[f];
                if (f < 207)      a0 += val;
                else if (f < 414) a1 += val;
                else              a2 += val;
            }
        }
        float vp0 = wave_sum64(a0) + vshaped[v * 3 + 0];
        float vp1 = wave_sum64(a1) + vshaped[v * 3 + 1];
        float vp2 = wave_sum64(a2) + vshaped[v * 3 + 2];

        float r0 = 0.f, r1 = 0.f, r2 = 0.f;
        if (lane < J_N) {
            float wgt = weights[(size_t)v * J_N + lane];
            const float* A = &sA[lane * 12];
            r0 = wgt * (A[0] * vp0 + A[1] * vp1 + A[2]  * vp2 + A[3]);
            r1 = wgt * (A[4] * vp0 + A[5] * vp1 + A[6]  * vp2 + A[7]);
            r2 = wgt * (A[8] * vp0 + A[9] * vp1 + A[10] * vp2 + A[11]);
        }
        float s0 = wave_sum64(r0);
        float s1 = wave_sum64(r1);
        float s2 = wave_sum64(r2);

        if (lane < 3) {
            float res = (lane == 0) ? s0 : (lane == 1) ? s1 : s2;
            out[v * 3 + lane] = res + trans[lane];
        }
        __syncthreads();   // drains next-group DMA + all waves done with buf[cur]
        cur ^= 1;
    }
}

extern "C" void kernel_launch(void* const* d_in, const int* in_sizes, int n_in,
                              void* d_out, int out_size, void* d_ws, size_t ws_size,
                              hipStream_t stream) {
    const float* beta      = (const float*)d_in[0];
    const float* pose      = (const float*)d_in[1];
    const float* trans     = (const float*)d_in[2];
    const float* shapedirs = (const float*)d_in[3];
    const float* v_template= (const float*)d_in[4];
    const float* J_reg     = (const float*)d_in[5];
    const float* posedirs  = (const float*)d_in[6];
    const float* weights   = (const float*)d_in[7];
    const int*   faces     = (const int*)d_in[8];

    float* out = (float*)d_out;

    // ws layout (floats)
    float* ws       = (float*)d_ws;
    float* vshaped  = ws;                 // 300000
    float* ws_lrot  = ws + 300080;        // 640
    float* ws_A     = ws + 300720;        // 288
    float* partials = ws + 301008;        // [c][72] = 3600

    kA_shape_faces<<<K1_BLK + F_BLK, 256, 0, stream>>>(shapedirs, v_template, beta, vshaped,
                                                       (const int4*)faces, out);
    kB_partial<<<dim3(CHUNKS, J_N), 256, 0, stream>>>(J_reg, vshaped, partials);
    kC_fk<<<1, 128, 0, stream>>>(pose, partials, ws_lrot, ws_A);
    kD_main<<<(V_N / 4) / GPB, 256, 0, stream>>>(posedirs, weights, vshaped, ws_lrot, ws_A, trans, out);
}

// Round 21
// 74.975 us; speedup vs baseline: 8.3846x; 1.0740x over previous
//
#include <hip/hip_runtime.h>

#define V_N 100000
#define J_N 24
#define NB_N 10
#define NP_N 207
#define FLAT_P 621
#define FACE_I 600000
#define CHUNKS 50
#define CHUNK_V 2000
#define K1_BLK 1172       // ceil(300000/256)
#define F_BLK  587        // ceil(150000/256)
#define VPW 8             // vertices per wave in kD (software pipeline depth 1)

__device__ __constant__ int PARENT_D[24] = {
    -1, 0, 0, 0, 1, 2, 3, 4, 5, 6, 7, 8, 9, 9, 9, 12, 13, 14, 16, 17, 18, 19, 20, 21
};

__device__ __forceinline__ float wave_sum64(float x) {
    float t;
    t = __int_as_float(__builtin_amdgcn_update_dpp(0, __float_as_int(x), 0x111, 0xf, 0xf, true)); x += t;
    t = __int_as_float(__builtin_amdgcn_update_dpp(0, __float_as_int(x), 0x112, 0xf, 0xf, true)); x += t;
    t = __int_as_float(__builtin_amdgcn_update_dpp(0, __float_as_int(x), 0x114, 0xf, 0xf, true)); x += t;
    t = __int_as_float(__builtin_amdgcn_update_dpp(0, __float_as_int(x), 0x118, 0xf, 0xf, true)); x += t;
    t = __int_as_float(__builtin_amdgcn_update_dpp(0, __float_as_int(x), 0x142, 0xa, 0xf, true)); x += t;
    t = __int_as_float(__builtin_amdgcn_update_dpp(0, __float_as_int(x), 0x143, 0xc, 0xf, true)); x += t;
    return __int_as_float(__builtin_amdgcn_readlane(__float_as_int(x), 63));
}

// ---------------- kA: shape blend + faces copy (R12-proven, unchanged) ----------------
__global__ __launch_bounds__(256) void kA_shape_faces(const float* __restrict__ shapedirs,
                                                      const float* __restrict__ vtemp,
                                                      const float* __restrict__ beta,
                                                      float* __restrict__ vshaped,
                                                      const int4* __restrict__ faces4,
                                                      float* __restrict__ out) {
    int b = blockIdx.x;
    if (b < K1_BLK) {
        int i = b * 256 + threadIdx.x;
        if (i >= V_N * 3) return;
        const float2* sd2 = reinterpret_cast<const float2*>(shapedirs + (size_t)i * NB_N);
        float2 p0 = sd2[0], p1 = sd2[1], p2 = sd2[2], p3 = sd2[3], p4 = sd2[4];
        float acc = vtemp[i];
        acc += p0.x * beta[0] + p0.y * beta[1];
        acc += p1.x * beta[2] + p1.y * beta[3];
        acc += p2.x * beta[4] + p2.y * beta[5];
        acc += p3.x * beta[6] + p3.y * beta[7];
        acc += p4.x * beta[8] + p4.y * beta[9];
        vshaped[i] = acc;
    } else {
        int i = (b - K1_BLK) * 256 + threadIdx.x;
        if (i < FACE_I / 4) {
            int4 f = faces4[i];
            float4* fdst = reinterpret_cast<float4*>(out + 300000);
            fdst[i] = make_float4((float)f.x, (float)f.y, (float)f.z, (float)f.w);
        }
    }
}

// ---------------- kB: partial GEMV — transposed partials [c][72] (R14-proven) ----------------
__global__ __launch_bounds__(256) void kB_partial(const float* __restrict__ Jreg,
                                                  const float* __restrict__ vshaped,
                                                  float* __restrict__ partials) {
    int c = blockIdx.x, j = blockIdx.y;
    int t = threadIdx.x;
    const float* row = Jreg + (size_t)j * V_N + (size_t)c * CHUNK_V;
    const float* vs  = vshaped + (size_t)c * CHUNK_V * 3;
    float s0 = 0.f, s1 = 0.f, s2 = 0.f;
    for (int i = t; i < CHUNK_V; i += 256) {
        float w = row[i];
        s0 += w * vs[i * 3 + 0];
        s1 += w * vs[i * 3 + 1];
        s2 += w * vs[i * 3 + 2];
    }
    for (int off = 32; off > 0; off >>= 1) {
        s0 += __shfl_xor(s0, off, 64);
        s1 += __shfl_xor(s1, off, 64);
        s2 += __shfl_xor(s2, off, 64);
    }
    __shared__ float ls[3][4];
    int wv = t >> 6;
    if ((t & 63) == 0) { ls[0][wv] = s0; ls[1][wv] = s1; ls[2][wv] = s2; }
    __syncthreads();
    if (t == 0) {
        float* p = partials + (size_t)c * 72 + j * 3;
        p[0] = ls[0][0] + ls[0][1] + ls[0][2] + ls[0][3];
        p[1] = ls[1][0] + ls[1][1] + ls[1][2] + ls[1][3];
        p[2] = ls[2][0] + ls[2][1] + ls[2][2] + ls[2][3];
    }
}

// ---------------- kC: parallel Jts reduce + Rodrigues + 640-lrot + FK + A (R15-proven) ----------------
__global__ __launch_bounds__(128) void kC_fk(const float* __restrict__ pose,
                                             const float* __restrict__ partials,
                                             float* __restrict__ ws_lrot,
                                             float* __restrict__ ws_A) {
    __shared__ float R[24][9];
    __shared__ float G[24][12];
    __shared__ float Jts[24][3];
    int t = threadIdx.x;
    if (t < 72) {
        float s = 0.f;
        #pragma unroll
        for (int c = 0; c < CHUNKS; ++c) s += partials[c * 72 + t];
        (&Jts[0][0])[t] = s;
    }
    if (t < 24) {
        float x = pose[t * 3 + 0], y = pose[t * 3 + 1], z = pose[t * 3 + 2];
        float th = sqrtf(x * x + y * y + z * z) + 1e-8f;
        float inv = 1.0f / th;
        float rx = x * inv, ry = y * inv, rz = z * inv;
        float c = cosf(th), s = sinf(th), ic = 1.0f - c;
        R[t][0] = c + ic * rx * rx;      R[t][1] = ic * rx * ry - s * rz;  R[t][2] = ic * rx * rz + s * ry;
        R[t][3] = ic * ry * rx + s * rz; R[t][4] = c + ic * ry * ry;       R[t][5] = ic * ry * rz - s * rx;
        R[t][6] = ic * rz * rx - s * ry; R[t][7] = ic * rz * ry + s * rx;  R[t][8] = c + ic * rz * rz;
    }
    __syncthreads();
    for (int f = t; f < 640; f += 128) {
        float val = 0.0f;
        if (f < FLAT_P) {
            int p = f % NP_N;
            int j = 1 + p / 9;
            int e = p % 9;
            val = R[j][e] - ((e == 0 || e == 4 || e == 8) ? 1.0f : 0.0f);
        }
        ws_lrot[f] = val;
    }
    if (t < 12) {
        int r = t >> 2, c = t & 3;
        G[0][t] = (c < 3) ? R[0][r * 3 + c] : Jts[0][r];
    }
    __syncthreads();
    for (int i = 1; i < J_N; ++i) {
        int p = PARENT_D[i];
        if (t < 12) {
            int r = t >> 2, c = t & 3;
            float sum = (c == 3) ? G[p][r * 4 + 3] : 0.0f;
            #pragma unroll
            for (int k = 0; k < 3; ++k) {
                float loc = (c < 3) ? R[i][k * 3 + c] : (Jts[i][k] - Jts[p][k]);
                sum += G[p][r * 4 + k] * loc;
            }
            G[i][t] = sum;
        }
        __syncthreads();
    }
    if (t < 72) {
        int j = t / 3, r = t % 3;
        float g0 = G[j][r * 4 + 0], g1 = G[j][r * 4 + 1], g2 = G[j][r * 4 + 2], g3 = G[j][r * 4 + 3];
        float corr = g0 * Jts[j][0] + g1 * Jts[j][1] + g2 * Jts[j][2];
        ws_A[j * 12 + r * 4 + 0] = g0;
        ws_A[j * 12 + r * 4 + 1] = g1;
        ws_A[j * 12 + r * 4 + 2] = g2;
        ws_A[j * 12 + r * 4 + 3] = g3 - corr;
    }
}

// ---------------- kD: pose blend + skinning — REGISTER software pipeline ----------------
// Wave owns VPW=8 consecutive vertices. Per iteration: issue next vertex's 10 independent
// dword loads into nf[] (waitcnt lands at the cf=nf copy), compute current vertex from cf[].
// ~2.5 KB/wave stays in flight through the whole compute tail -> continuous HBM demand.
// No barriers in the loop; LDS holds only the tables (one prologue barrier).
__global__ __launch_bounds__(256) void kD_main(const float* __restrict__ posedirs,
                                               const float* __restrict__ weights,
                                               const float* __restrict__ vshaped,
                                               const float* __restrict__ ws_lrot,
                                               const float* __restrict__ ws_A,
                                               const float* __restrict__ trans,
                                               float* __restrict__ out) {
    __shared__ float sL[640];
    __shared__ float sA[288];
    int tid = threadIdx.x;
    for (int i = tid; i < 640; i += 256) sL[i] = ws_lrot[i];
    for (int i = tid; i < 288; i += 256) sA[i] = ws_A[i];
    __syncthreads();

    int lane = tid & 63;
    int w = tid >> 6;
    int vbase = (blockIdx.x * 4 + w) * VPW;   // grid exact: V_N/(4*VPW) blocks

    float cf[10];
    {
        const float* pd = posedirs + (size_t)vbase * FLAT_P;
        #pragma unroll
        for (int k = 0; k < 10; ++k) {
            int f = lane + k * 64;
            cf[k] = (f < FLAT_P) ? pd[f] : 0.0f;
        }
    }

    #pragma unroll 1
    for (int i = 0; i < VPW; ++i) {
        int v = vbase + i;

        // prefetch next vertex (independent loads; in flight during compute below)
        float nf[10];
        if (i + 1 < VPW) {
            const float* pd = posedirs + (size_t)(v + 1) * FLAT_P;
            #pragma unroll
            for (int k = 0; k < 10; ++k) {
                int f = lane + k * 64;
                nf[k] = (f < FLAT_P) ? pd[f] : 0.0f;
            }
        } else {
            #pragma unroll
            for (int k = 0; k < 10; ++k) nf[k] = 0.0f;
        }

        // compute current vertex (R12-proven math)
        float a0 = 0.f, a1 = 0.f, a2 = 0.f;
        #pragma unroll
        for (int k = 0; k < 10; ++k) {
            int f = lane + k * 64;
            if (f < FLAT_P) {
                float val = cf[k] * sL[f];
                if (f < 207)      a0 += val;
                else if (f < 414) a1 += val;
                else              a2 += val;
            }
        }
        float vp0 = wave_sum64(a0) + vshaped[v * 3 + 0];
        float vp1 = wave_sum64(a1) + vshaped[v * 3 + 1];
        float vp2 = wave_sum64(a2) + vshaped[v * 3 + 2];

        float r0 = 0.f, r1 = 0.f, r2 = 0.f;
        if (lane < J_N) {
            float wgt = weights[(size_t)v * J_N + lane];
            const float* A = &sA[lane * 12];
            r0 = wgt * (A[0] * vp0 + A[1] * vp1 + A[2]  * vp2 + A[3]);
            r1 = wgt * (A[4] * vp0 + A[5] * vp1 + A[6]  * vp2 + A[7]);
            r2 = wgt * (A[8] * vp0 + A[9] * vp1 + A[10] * vp2 + A[11]);
        }
        float s0 = wave_sum64(r0);
        float s1 = wave_sum64(r1);
        float s2 = wave_sum64(r2);

        if (lane < 3) {
            float res = (lane == 0) ? s0 : (lane == 1) ? s1 : s2;
            out[v * 3 + lane] = res + trans[lane];
        }

        #pragma unroll
        for (int k = 0; k < 10; ++k) cf[k] = nf[k];
    }
}

extern "C" void kernel_launch(void* const* d_in, const int* in_sizes, int n_in,
                              void* d_out, int out_size, void* d_ws, size_t ws_size,
                              hipStream_t stream) {
    const float* beta      = (const float*)d_in[0];
    const float* pose      = (const float*)d_in[1];
    const float* trans     = (const float*)d_in[2];
    const float* shapedirs = (const float*)d_in[3];
    const float* v_template= (const float*)d_in[4];
    const float* J_reg     = (const float*)d_in[5];
    const float* posedirs  = (const float*)d_in[6];
    const float* weights   = (const float*)d_in[7];
    const int*   faces     = (const int*)d_in[8];

    float* out = (float*)d_out;

    // ws layout (floats)
    float* ws       = (float*)d_ws;
    float* vshaped  = ws;                 // 300000
    float* ws_lrot  = ws + 300080;        // 640
    float* ws_A     = ws + 300720;        // 288
    float* partials = ws + 301008;        // [c][72] = 3600

    kA_shape_faces<<<K1_BLK + F_BLK, 256, 0, stream>>>(shapedirs, v_template, beta, vshaped,
                                                       (const int4*)faces, out);
    kB_partial<<<dim3(CHUNKS, J_N), 256, 0, stream>>>(J_reg, vshaped, partials);
    kC_fk<<<1, 128, 0, stream>>>(pose, partials, ws_lrot, ws_A);
    kD_main<<<V_N / (4 * VPW), 256, 0, stream>>>(posedirs, weights, vshaped, ws_lrot, ws_A, trans, out);
}